// Round 2
// baseline (214.586 us; speedup 1.0000x reference)
//
#include <hip/hip_runtime.h>

// yoloLoss on MI355X — memory-bound streaming reduction.
// pred/target: (4096,14,14,30) fp32. Output: scalar fp32.
//
// R2: R0/R1 showed time is invariant to occupancy (2 vs 5 blocks/CU: identical
// 73.5us, VALUBusy 7%, hbm 16%). Implied ~225cy per wave-load = exposed L2
// latency: the load->VGPR->ds_write staging plus __syncthreads (which drains
// vmcnt(0)) serializes memory phases. Fix per GEMM ladder (m97/m218):
//  - global_load_lds width=16 (no VGPR round trip),
//  - double-buffered tiles + counted vmcnt(16) across RAW s_barriers
//    (prefetch of tile k+1/k+2 never drained inside the loop),
//  - 256 persistent blocks (1/CU, 120KB LDS), 12-13 contiguous tiles each.
// Numerics: per-tile partials, same lane<->cell map, same shuffle tree, same
// scalar cls loop -> bitwise-identical output; reduce kernel unchanged.

#define FEAT 30               // B*5 + C
#define CELLS 802816          // 4096*14*14
#define TPB 256
#define CPB 256               // cells per tile
#define NTILES (CELLS / CPB)  // 3136
#define NBLK 256              // persistent blocks: 1 per CU
#define F4T (CPB * FEAT / 4)  // 1920 float4 per array per tile

typedef __attribute__((address_space(1))) const unsigned int gas_u32;
typedef __attribute__((address_space(3))) unsigned int las_u32;

__device__ __forceinline__ void gld_lds16(const float4* g, float4* l) {
    // 16B per lane, LDS dest = wave-uniform base + lane*16 (linear layout ok)
    __builtin_amdgcn_global_load_lds((gas_u32*)g, (las_u32*)l, 16, 0, 0);
}

__device__ __forceinline__ float iou_f(float x1, float y1, float w1, float h1,
                                       float x2, float y2, float w2, float h2) {
    float b1x1 = x1 - 0.5f * w1, b1x2 = x1 + 0.5f * w1;
    float b1y1 = y1 - 0.5f * h1, b1y2 = y1 + 0.5f * h1;
    float b2x1 = x2 - 0.5f * w2, b2x2 = x2 + 0.5f * w2;
    float b2y1 = y2 - 0.5f * h2, b2y2 = y2 + 0.5f * h2;
    float iw = fmaxf(fminf(b1x2, b2x2) - fmaxf(b1x1, b2x1), 0.0f);
    float ih = fmaxf(fminf(b1y2, b2y2) - fmaxf(b1y1, b2y1), 0.0f);
    float inter = iw * ih;
    float a1 = (b1x2 - b1x1) * (b1y2 - b1y1);
    float a2 = (b2x2 - b2x1) * (b2y2 - b2y1);
    return inter / (a1 + a2 - inter + 1e-6f);
}

__global__ __launch_bounds__(TPB, 1) void yolo_main_kernel(
        const float* __restrict__ pred, const float* __restrict__ tgt,
        float* __restrict__ partials) {
    // 2 x (pred,tgt) tile buffers = 122880 B (<=128KB/WG per 8-phase precedent)
    __shared__ float4 bP[2][F4T];
    __shared__ float4 bT[2][F4T];
    __shared__ float wave_sum[4];

    const int tid  = threadIdx.x;
    const int w    = tid >> 6;
    const int lane = tid & 63;
    const int b    = blockIdx.x;
    // blocks 0..63 own 13 tiles, 64..255 own 12 (64*13 + 192*12 = 3136)
    const int t0 = b * 12 + (b < 64 ? b : 64);
    const int nt = (b < 64) ? 13 : 12;

    const float4* pred4 = (const float4*)pred;
    const float4* tgt4  = (const float4*)tgt;

    // Issue one tile's loads into parity pp: 16 gll per wave (8 pred + 8 tgt).
    auto stage = [&](int k, int pp) {
        const float4* gp = pred4 + (long long)(t0 + k) * F4T;
        const float4* gt = tgt4  + (long long)(t0 + k) * F4T;
#pragma unroll
        for (int s = 0; s < 7; ++s) {
            const int idx = s * 256 + w * 64;
            gld_lds16(gp + idx + lane, &bP[pp][idx]);
            gld_lds16(gt + idx + lane, &bT[pp][idx]);
        }
        // tail 128 float4: 32 per wave, lanes 0..31 active
        if (lane < 32) {
            const int idx = 1792 + w * 32;
            gld_lds16(gp + idx + lane, &bP[pp][idx]);
            gld_lds16(gt + idx + lane, &bT[pp][idx]);
        }
    };

    stage(0, 0);
    if (nt > 1) stage(1, 1);

    for (int k = 0; k < nt; ++k) {
        const int pp = k & 1;

        // Tile k ready: keep tile k+1's 16 loads/wave in flight (T4).
        if (k < nt - 1) asm volatile("s_waitcnt vmcnt(16)" ::: "memory");
        else            asm volatile("s_waitcnt vmcnt(0)"  ::: "memory");
        __builtin_amdgcn_sched_barrier(0);
        __builtin_amdgcn_s_barrier();   // raw: no vmcnt drain
        __builtin_amdgcn_sched_barrier(0);

        // LDS -> regs: this thread's cell (30 floats each, 15 float2 loads)
        const float2* pc = (const float2*)((const float*)bP[pp] + tid * FEAT);
        const float2* tc = (const float2*)((const float*)bT[pp] + tid * FEAT);
        float p[FEAT], t[FEAT];
#pragma unroll
        for (int i = 0; i < FEAT / 2; ++i) {
            float2 v = pc[i]; p[2 * i] = v.x; p[2 * i + 1] = v.y;
        }
#pragma unroll
        for (int i = 0; i < FEAT / 2; ++i) {
            float2 v = tc[i]; t[2 * i] = v.x; t[2 * i + 1] = v.y;
        }
        // All reads complete before any wave may overwrite buffers[pp].
        asm volatile("s_waitcnt lgkmcnt(0)" ::: "memory");
        __builtin_amdgcn_sched_barrier(0);
        __builtin_amdgcn_s_barrier();
        __builtin_amdgcn_sched_barrier(0);

        // Prefetch tile k+2 into the buffer we just released; its latency
        // hides under compute+reduce and next iter's top wait is counted.
        if (k + 2 < nt) stage(k + 2, pp);

        // --- per-cell YOLO loss (identical to verified R0/R1 math) ---
        const bool obj0 = t[4] > 0.0f;
        const bool obj1 = t[9] > 0.0f;
        const float mf = obj0 ? 1.0f : 0.0f;

        float d0 = p[4] - t[4];
        float d1 = p[9] - t[9];
        float noobj = (obj0 ? 0.0f : d0 * d0) + (obj1 ? 0.0f : d1 * d1);

        float iou0 = iou_f(p[0], p[1], p[2], p[3], t[0], t[1], t[2], t[3]);
        float iou1 = iou_f(p[5], p[6], p[7], p[8], t[5], t[6], t[7], t[8]);
        const bool sel1 = iou1 > iou0;

        float pbx = sel1 ? p[5] : p[0];
        float pby = sel1 ? p[6] : p[1];
        float pbw = sel1 ? p[7] : p[2];
        float pbh = sel1 ? p[8] : p[3];
        float pbc = sel1 ? p[9] : p[4];
        float tbx = sel1 ? t[5] : t[0];
        float tby = sel1 ? t[6] : t[1];
        float tbw = sel1 ? t[7] : t[2];
        float tbh = sel1 ? t[8] : t[3];
        float tbc = sel1 ? t[9] : t[4];

        float dx = pbx - tbx, dy = pby - tby;
        float xy = dx * dx + dy * dy;

        float pw = sqrtf(fabsf(pbw) + 1e-6f);
        float ph = sqrtf(fabsf(pbh) + 1e-6f);
        float tw = sqrtf(obj0 ? tbw : 1.0f);
        float th = sqrtf(obj0 ? tbh : 1.0f);
        float dw = pw - tw, dh = ph - th;
        float wh = dw * dw + dh * dh;

        float dc = pbc - tbc;
        float obj_l = dc * dc;

        float nonbest = (p[4] + p[9]) - pbc;
        noobj += 0.5f * mf * nonbest * nonbest;

        float cls = 0.0f;
#pragma unroll
        for (int q = 10; q < FEAT; ++q) {
            float d = p[q] - t[q];
            cls += d * d;
        }

        float cell = 5.0f * mf * (xy + wh) + mf * obj_l + 0.5f * noobj + mf * cls;

        // --- reduction: same tree as before (bitwise-identical partials) ---
        float v = cell;
#pragma unroll
        for (int off = 32; off > 0; off >>= 1) v += __shfl_down(v, off, 64);
        if (lane == 0) wave_sum[w] = v;
        asm volatile("s_waitcnt lgkmcnt(0)" ::: "memory");
        __builtin_amdgcn_sched_barrier(0);
        __builtin_amdgcn_s_barrier();   // raw: outstanding prefetch unaffected
        __builtin_amdgcn_sched_barrier(0);
        if (tid == 0)
            partials[t0 + k] =
                wave_sum[0] + wave_sum[1] + wave_sum[2] + wave_sum[3];
        // wave_sum reuse is safe: next write happens only after next iter's
        // barriers, and tid0's reads retire before it reaches them.
    }
}

__global__ __launch_bounds__(TPB) void yolo_reduce_kernel(
        const float* __restrict__ partials, float* __restrict__ out) {
    __shared__ float wave_sum[TPB / 64];
    const int tid = threadIdx.x;
    float v = 0.0f;
    for (int i = tid; i < NTILES; i += TPB) v += partials[i];
#pragma unroll
    for (int off = 32; off > 0; off >>= 1) v += __shfl_down(v, off, 64);
    if ((tid & 63) == 0) wave_sum[tid >> 6] = v;
    __syncthreads();
    if (tid == 0)
        out[0] = (wave_sum[0] + wave_sum[1] + wave_sum[2] + wave_sum[3]) *
                 (1.0f / 4096.0f);
}

extern "C" void kernel_launch(void* const* d_in, const int* in_sizes, int n_in,
                              void* d_out, int out_size, void* d_ws, size_t ws_size,
                              hipStream_t stream) {
    const float* pred = (const float*)d_in[0];
    const float* tgt  = (const float*)d_in[1];
    float* out = (float*)d_out;
    float* partials = (float*)d_ws; // 3136 floats

    yolo_main_kernel<<<NBLK, TPB, 0, stream>>>(pred, tgt, partials);
    yolo_reduce_kernel<<<1, TPB, 0, stream>>>(partials, out);
}

// Round 4
// 190.667 us; speedup vs baseline: 1.1255x; 1.1255x over previous
//
#include <hip/hip_runtime.h>

// yoloLoss on MI355X — memory-bound streaming reduction.
// pred/target: (4096,14,14,30) fp32. Output: scalar fp32.
//
// R4 (= R3 retry): R0/R1/R2 — three schedules (occupancy 15/42/10%) all
// pinned at 72-85us. Not schedule-bound. Key counter: WRITE_SIZE ~100MB on
// a dispatch that writes 12.5KB => dirty-line writebacks. The harness
// re-poisons the 192MB inputs between iterations; our read misses allocate
// and evict those dirty lines => every miss = fetch + victim writeback
// (194MB combined @ 2.6TB/s). Fix: NON-TEMPORAL staging loads (nt flag):
// still hit dirty cache lines, but don't allocate/promote => no eviction
// storm. Structure = R1 (equal-fastest, 31KB LDS, 5 blocks/CU), loads -> nt.
// Build fix vs R3: __builtin_nontemporal_load needs a native clang
// ext_vector type, not HIP_vector_type<float,4>.
// Numerics identical: same tiles, same lane<->cell map, same reduce tree.

#define FEAT 30               // B*5 + C = 2*5 + 20
#define CELLS 802816          // 4096*14*14
#define TPB 256               // threads per block
#define CPB 256               // cells per block (1 cell/thread)
#define NBLOCKS (CELLS / CPB) // 3136 exactly
#define F4_PER_ARRAY (CPB * FEAT / 4) // 1920 float4 per array per tile

typedef float f32x4 __attribute__((ext_vector_type(4)));

__device__ __forceinline__ float iou_f(float x1, float y1, float w1, float h1,
                                       float x2, float y2, float w2, float h2) {
    float b1x1 = x1 - 0.5f * w1, b1x2 = x1 + 0.5f * w1;
    float b1y1 = y1 - 0.5f * h1, b1y2 = y1 + 0.5f * h1;
    float b2x1 = x2 - 0.5f * w2, b2x2 = x2 + 0.5f * w2;
    float b2y1 = y2 - 0.5f * h2, b2y2 = y2 + 0.5f * h2;
    float iw = fmaxf(fminf(b1x2, b2x2) - fmaxf(b1x1, b2x1), 0.0f);
    float ih = fmaxf(fminf(b1y2, b2y2) - fmaxf(b1y1, b2y1), 0.0f);
    float inter = iw * ih;
    float a1 = (b1x2 - b1x1) * (b1y2 - b1y1);
    float a2 = (b2x2 - b2x1) * (b2y2 - b2y1);
    return inter / (a1 + a2 - inter + 1e-6f);
}

__global__ __launch_bounds__(TPB, 5) void yolo_main_kernel(
        const float* __restrict__ pred, const float* __restrict__ tgt,
        float* __restrict__ partials) {
    // 30720 B tile buffer, staged twice per block. 160K/30.7K = 5 blocks/CU.
    __shared__ float sb[CPB * FEAT];
    __shared__ float wave_sum[TPB / 64];

    const int tid = threadIdx.x;
    const long long base = (long long)blockIdx.x * (CPB * FEAT);

    // ---- Phase 1: stage pred tile (coalesced nt float4), read cell to regs ----
    {
        const f32x4* g = (const f32x4*)(pred + base);
        f32x4* l = (f32x4*)sb;
#pragma unroll
        for (int i = 0; i < 7; ++i)
            l[tid + i * TPB] = __builtin_nontemporal_load(&g[tid + i * TPB]);
        if (tid < (F4_PER_ARRAY - 7 * TPB)) // tail: 128 float4
            l[tid + 7 * TPB] = __builtin_nontemporal_load(&g[tid + 7 * TPB]);
    }
    __syncthreads();

    float p[FEAT];
    {
        const float2* pc = (const float2*)(sb + tid * FEAT); // 8B-aligned
#pragma unroll
        for (int i = 0; i < FEAT / 2; ++i) {
            float2 v = pc[i];
            p[2 * i] = v.x;
            p[2 * i + 1] = v.y;
        }
    }
    __syncthreads(); // all pred reads done before buffer overwrite

    // ---- Phase 2: stage tgt tile into the SAME buffer ----
    {
        const f32x4* g = (const f32x4*)(tgt + base);
        f32x4* l = (f32x4*)sb;
#pragma unroll
        for (int i = 0; i < 7; ++i)
            l[tid + i * TPB] = __builtin_nontemporal_load(&g[tid + i * TPB]);
        if (tid < (F4_PER_ARRAY - 7 * TPB))
            l[tid + 7 * TPB] = __builtin_nontemporal_load(&g[tid + 7 * TPB]);
    }
    __syncthreads();

    const float2* tc = (const float2*)(sb + tid * FEAT);
    float t[10];
#pragma unroll
    for (int i = 0; i < 5; ++i) { // box region: t[0..9]
        float2 v = tc[i];
        t[2 * i] = v.x;
        t[2 * i + 1] = v.y;
    }

    // --- per-cell YOLO loss (mirrors the JAX reference exactly) ---
    const bool obj0 = t[4] > 0.0f;   // box0 conf target
    const bool obj1 = t[9] > 0.0f;   // box1 conf target
    const float mf = obj0 ? 1.0f : 0.0f; // has_obj = obj_mask[...,0]

    float d0 = p[4] - t[4];
    float d1 = p[9] - t[9];
    float noobj = (obj0 ? 0.0f : d0 * d0) + (obj1 ? 0.0f : d1 * d1);

    float iou0 = iou_f(p[0], p[1], p[2], p[3], t[0], t[1], t[2], t[3]);
    float iou1 = iou_f(p[5], p[6], p[7], p[8], t[5], t[6], t[7], t[8]);
    const bool sel1 = iou1 > iou0;

    float pbx = sel1 ? p[5] : p[0];
    float pby = sel1 ? p[6] : p[1];
    float pbw = sel1 ? p[7] : p[2];
    float pbh = sel1 ? p[8] : p[3];
    float pbc = sel1 ? p[9] : p[4];
    float tbx = sel1 ? t[5] : t[0];
    float tby = sel1 ? t[6] : t[1];
    float tbw = sel1 ? t[7] : t[2];
    float tbh = sel1 ? t[8] : t[3];
    float tbc = sel1 ? t[9] : t[4];

    float dx = pbx - tbx, dy = pby - tby;
    float xy = dx * dx + dy * dy;

    float pw = sqrtf(fabsf(pbw) + 1e-6f);
    float ph = sqrtf(fabsf(pbh) + 1e-6f);
    float tw = sqrtf(obj0 ? tbw : 1.0f); // t_wh_safe: avoids NaN when !obj
    float th = sqrtf(obj0 ? tbh : 1.0f);
    float dw = pw - tw, dh = ph - th;
    float wh = dw * dw + dh * dh;

    float dc = pbc - tbc;
    float obj_l = dc * dc;

    // nonbest conf: LAMBDA_NOOBJ applied here AND again in total (ref does both)
    float nonbest = (p[4] + p[9]) - pbc;
    noobj += 0.5f * mf * nonbest * nonbest;

    // class loss: stream t[10..29] straight from LDS, accumulate
    float cls = 0.0f;
#pragma unroll
    for (int i = 5; i < FEAT / 2; ++i) {
        float2 v = tc[i];
        float da = p[2 * i] - v.x;
        float db = p[2 * i + 1] - v.y;
        cls += da * da + db * db;
    }

    float cell = 5.0f * mf * (xy + wh) + mf * obj_l + 0.5f * noobj + mf * cls;

    // --- block reduction: wave shuffle then LDS across 4 waves ---
    float v = cell;
#pragma unroll
    for (int off = 32; off > 0; off >>= 1) v += __shfl_down(v, off, 64);
    if ((tid & 63) == 0) wave_sum[tid >> 6] = v;
    __syncthreads();
    if (tid == 0)
        partials[blockIdx.x] = wave_sum[0] + wave_sum[1] + wave_sum[2] + wave_sum[3];
}

__global__ __launch_bounds__(TPB) void yolo_reduce_kernel(
        const float* __restrict__ partials, float* __restrict__ out) {
    __shared__ float wave_sum[TPB / 64];
    const int tid = threadIdx.x;
    float v = 0.0f;
    for (int i = tid; i < NBLOCKS; i += TPB) v += partials[i];
#pragma unroll
    for (int off = 32; off > 0; off >>= 1) v += __shfl_down(v, off, 64);
    if ((tid & 63) == 0) wave_sum[tid >> 6] = v;
    __syncthreads();
    if (tid == 0)
        out[0] = (wave_sum[0] + wave_sum[1] + wave_sum[2] + wave_sum[3]) *
                 (1.0f / 4096.0f);
}

extern "C" void kernel_launch(void* const* d_in, const int* in_sizes, int n_in,
                              void* d_out, int out_size, void* d_ws, size_t ws_size,
                              hipStream_t stream) {
    const float* pred = (const float*)d_in[0];
    const float* tgt  = (const float*)d_in[1];
    float* out = (float*)d_out;
    float* partials = (float*)d_ws; // 3136 floats = 12.5 KB, << ws_size

    yolo_main_kernel<<<NBLOCKS, TPB, 0, stream>>>(pred, tgt, partials);
    yolo_reduce_kernel<<<1, TPB, 0, stream>>>(partials, out);
}

// Round 5
// 189.117 us; speedup vs baseline: 1.1347x; 1.0082x over previous
//
#include <hip/hip_runtime.h>

// yoloLoss on MI355X — memory-bound streaming reduction.
// pred/target: (4096,14,14,30) fp32. Output: scalar fp32.
//
// R5: R4's nt-loads killed the writeback storm (total 205.6->190.7us; main
// ~73.5 -> ~58us, now below the harness's 57us fill dispatches). Remaining
// gap to the ~31us stream floor: the R1 structure serializes two full
// global-load latencies per block (pred phase, barrier, LDS round-trip,
// THEN tgt loads issue). R1/R2's null results on scheduling were measured
// in the storm regime and don't transfer. Fix = T14 issue-early/write-late:
// issue all 15 nt loads (pred+tgt) into VGPRs up front (sched_barrier pins
// them), write pred to LDS under a counted vmcnt (tgt stays in flight),
// do the pred LDS round-trip while tgt flies, then write tgt. One exposed
// latency instead of two. LDS stays 30.7KB; launch_bounds(256,4) caps
// VGPR at 128 (live set ~70, no spill).
// Numerics identical: same tiles, lane<->cell map, reduce tree.

#define FEAT 30               // B*5 + C = 2*5 + 20
#define CELLS 802816          // 4096*14*14
#define TPB 256               // threads per block
#define CPB 256               // cells per block (1 cell/thread)
#define NBLOCKS (CELLS / CPB) // 3136 exactly
#define F4_PER_ARRAY (CPB * FEAT / 4) // 1920 float4 per array per tile

typedef float f32x4 __attribute__((ext_vector_type(4)));

__device__ __forceinline__ float iou_f(float x1, float y1, float w1, float h1,
                                       float x2, float y2, float w2, float h2) {
    float b1x1 = x1 - 0.5f * w1, b1x2 = x1 + 0.5f * w1;
    float b1y1 = y1 - 0.5f * h1, b1y2 = y1 + 0.5f * h1;
    float b2x1 = x2 - 0.5f * w2, b2x2 = x2 + 0.5f * w2;
    float b2y1 = y2 - 0.5f * h2, b2y2 = y2 + 0.5f * h2;
    float iw = fmaxf(fminf(b1x2, b2x2) - fmaxf(b1x1, b2x1), 0.0f);
    float ih = fmaxf(fminf(b1y2, b2y2) - fmaxf(b1y1, b2y1), 0.0f);
    float inter = iw * ih;
    float a1 = (b1x2 - b1x1) * (b1y2 - b1y1);
    float a2 = (b2x2 - b2x1) * (b2y2 - b2y1);
    return inter / (a1 + a2 - inter + 1e-6f);
}

__global__ __launch_bounds__(TPB, 4) void yolo_main_kernel(
        const float* __restrict__ pred, const float* __restrict__ tgt,
        float* __restrict__ partials) {
    // 30720 B tile buffer, written twice per block (pred then tgt).
    __shared__ float sb[CPB * FEAT];
    __shared__ float wave_sum[TPB / 64];

    const int tid = threadIdx.x;
    const long long base = (long long)blockIdx.x * (CPB * FEAT);
    const bool tail = tid < (F4_PER_ARRAY - 7 * TPB); // 128 float4 tail

    const f32x4* gp = (const f32x4*)(pred + base);
    const f32x4* gt = (const f32x4*)(tgt + base);
    f32x4* l = (f32x4*)sb;

    // ---- Issue ALL loads up front (15-16 nt loads/thread in flight) ----
    f32x4 pr[8], tr[8];
#pragma unroll
    for (int i = 0; i < 7; ++i)
        pr[i] = __builtin_nontemporal_load(&gp[tid + i * TPB]);
    if (tail) pr[7] = __builtin_nontemporal_load(&gp[tid + 7 * TPB]);
#pragma unroll
    for (int i = 0; i < 7; ++i)
        tr[i] = __builtin_nontemporal_load(&gt[tid + i * TPB]);
    if (tail) tr[7] = __builtin_nontemporal_load(&gt[tid + 7 * TPB]);
    // Pin issue order: scheduler must not sink the tgt loads below the
    // pred LDS writes / barrier (that would re-serialize the two latencies).
    __builtin_amdgcn_sched_barrier(0);

    // ---- Phase 1: pred -> LDS (counted vmcnt: tgt loads stay in flight) ----
#pragma unroll
    for (int i = 0; i < 7; ++i) l[tid + i * TPB] = pr[i];
    if (tail) l[tid + 7 * TPB] = pr[7];
    __syncthreads();

    float p[FEAT];
    {
        const float2* pc = (const float2*)(sb + tid * FEAT); // 8B-aligned
#pragma unroll
        for (int i = 0; i < FEAT / 2; ++i) {
            float2 v = pc[i];
            p[2 * i] = v.x;
            p[2 * i + 1] = v.y;
        }
    }
    __syncthreads(); // all pred reads done before buffer overwrite

    // ---- Phase 2: tgt -> LDS (latency already hidden under phase 1) ----
#pragma unroll
    for (int i = 0; i < 7; ++i) l[tid + i * TPB] = tr[i];
    if (tail) l[tid + 7 * TPB] = tr[7];
    __syncthreads();

    const float2* tc = (const float2*)(sb + tid * FEAT);
    float t[10];
#pragma unroll
    for (int i = 0; i < 5; ++i) { // box region: t[0..9]
        float2 v = tc[i];
        t[2 * i] = v.x;
        t[2 * i + 1] = v.y;
    }

    // --- per-cell YOLO loss (mirrors the JAX reference exactly) ---
    const bool obj0 = t[4] > 0.0f;   // box0 conf target
    const bool obj1 = t[9] > 0.0f;   // box1 conf target
    const float mf = obj0 ? 1.0f : 0.0f; // has_obj = obj_mask[...,0]

    float d0 = p[4] - t[4];
    float d1 = p[9] - t[9];
    float noobj = (obj0 ? 0.0f : d0 * d0) + (obj1 ? 0.0f : d1 * d1);

    float iou0 = iou_f(p[0], p[1], p[2], p[3], t[0], t[1], t[2], t[3]);
    float iou1 = iou_f(p[5], p[6], p[7], p[8], t[5], t[6], t[7], t[8]);
    const bool sel1 = iou1 > iou0;

    float pbx = sel1 ? p[5] : p[0];
    float pby = sel1 ? p[6] : p[1];
    float pbw = sel1 ? p[7] : p[2];
    float pbh = sel1 ? p[8] : p[3];
    float pbc = sel1 ? p[9] : p[4];
    float tbx = sel1 ? t[5] : t[0];
    float tby = sel1 ? t[6] : t[1];
    float tbw = sel1 ? t[7] : t[2];
    float tbh = sel1 ? t[8] : t[3];
    float tbc = sel1 ? t[9] : t[4];

    float dx = pbx - tbx, dy = pby - tby;
    float xy = dx * dx + dy * dy;

    float pw = sqrtf(fabsf(pbw) + 1e-6f);
    float ph = sqrtf(fabsf(pbh) + 1e-6f);
    float tw = sqrtf(obj0 ? tbw : 1.0f); // t_wh_safe: avoids NaN when !obj
    float th = sqrtf(obj0 ? tbh : 1.0f);
    float dw = pw - tw, dh = ph - th;
    float wh = dw * dw + dh * dh;

    float dc = pbc - tbc;
    float obj_l = dc * dc;

    // nonbest conf: LAMBDA_NOOBJ applied here AND again in total (ref does both)
    float nonbest = (p[4] + p[9]) - pbc;
    noobj += 0.5f * mf * nonbest * nonbest;

    // class loss: stream t[10..29] straight from LDS, accumulate
    float cls = 0.0f;
#pragma unroll
    for (int i = 5; i < FEAT / 2; ++i) {
        float2 v = tc[i];
        float da = p[2 * i] - v.x;
        float db = p[2 * i + 1] - v.y;
        cls += da * da + db * db;
    }

    float cell = 5.0f * mf * (xy + wh) + mf * obj_l + 0.5f * noobj + mf * cls;

    // --- block reduction: wave shuffle then LDS across 4 waves ---
    float v = cell;
#pragma unroll
    for (int off = 32; off > 0; off >>= 1) v += __shfl_down(v, off, 64);
    if ((tid & 63) == 0) wave_sum[tid >> 6] = v;
    __syncthreads();
    if (tid == 0)
        partials[blockIdx.x] = wave_sum[0] + wave_sum[1] + wave_sum[2] + wave_sum[3];
}

__global__ __launch_bounds__(TPB) void yolo_reduce_kernel(
        const float* __restrict__ partials, float* __restrict__ out) {
    __shared__ float wave_sum[TPB / 64];
    const int tid = threadIdx.x;
    float v = 0.0f;
    for (int i = tid; i < NBLOCKS; i += TPB) v += partials[i];
#pragma unroll
    for (int off = 32; off > 0; off >>= 1) v += __shfl_down(v, off, 64);
    if ((tid & 63) == 0) wave_sum[tid >> 6] = v;
    __syncthreads();
    if (tid == 0)
        out[0] = (wave_sum[0] + wave_sum[1] + wave_sum[2] + wave_sum[3]) *
                 (1.0f / 4096.0f);
}

extern "C" void kernel_launch(void* const* d_in, const int* in_sizes, int n_in,
                              void* d_out, int out_size, void* d_ws, size_t ws_size,
                              hipStream_t stream) {
    const float* pred = (const float*)d_in[0];
    const float* tgt  = (const float*)d_in[1];
    float* out = (float*)d_out;
    float* partials = (float*)d_ws; // 3136 floats = 12.5 KB, << ws_size

    yolo_main_kernel<<<NBLOCKS, TPB, 0, stream>>>(pred, tgt, partials);
    yolo_reduce_kernel<<<1, TPB, 0, stream>>>(partials, out);
}